// Round 1
// baseline (76.520 us; speedup 1.0000x reference)
//
#include <hip/hip_runtime.h>
#include <math.h>

// Exact MAP over 2^8 binary configs per pixel.
// Key algebra: argmax_k [ sum_t (s_t? log p_t : log(1-p_t)) + sum_n (d_n? log c_n : log(1-c_n)) ]
//            = argmax_k [ sum_t s_t * logit(p_t) + sum_n d_n * logit(c_n) ]   (constant dropped)
// If no edge couples bits {0..3} with bits {4..7}, the argmax decomposes into
// two independent 16-way maxes (true for edges [[0,1],[2,3],[4,5],[6,7]]).
// Generic 256-config fallback retained for cross edges (uniform branch).

#define EPS 1e-6f

__global__ __launch_bounds__(256) void map_mrf_kernel(
    const float* __restrict__ o_seg,  // [B, T, HW]
    const float* __restrict__ o_ch,   // [B, N, HW]
    const int*   __restrict__ edges,  // [N, 2]
    float*       __restrict__ out)    // [B, T, HW]
{
    constexpr int T  = 8;
    constexpr int N  = 4;
    constexpr int HW = 256 * 256;
    constexpr int TOTAL = 4 * HW;  // B * HW

    int i = blockIdx.x * blockDim.x + threadIdx.x;
    if (i >= TOTAL) return;
    int b  = i >> 16;          // i / HW
    int hw = i & (HW - 1);     // i % HW

    const float* ps = o_seg + (size_t)b * T * HW + hw;
    const float* cs = o_ch  + (size_t)b * N * HW + hw;

    // logits of unary probabilities
    float a[T];
    #pragma unroll
    for (int t = 0; t < T; ++t) {
        float p = ps[(size_t)t * HW];
        p = fminf(fmaxf(p, EPS), 1.0f - EPS);
        a[t] = logf(p) - log1pf(-p);
    }

    // logits of change probabilities + edge endpoints (uniform across threads)
    float bn[N];
    int eu[N], ev[N];
    bool cross = false;
    #pragma unroll
    for (int n = 0; n < N; ++n) {
        float c = cs[(size_t)n * HW];
        c = fminf(fmaxf(c, EPS), 1.0f - EPS);
        bn[n] = logf(c) - log1pf(-c);
        eu[n] = edges[2 * n];
        ev[n] = edges[2 * n + 1];
        bool lo = (eu[n] < 4) && (ev[n] < 4);
        bool hi = (eu[n] >= 4) && (ev[n] >= 4);
        if (!lo && !hi) cross = true;
    }

    int best;
    if (!cross) {
        // ---- decomposed path: independent argmax over low/high nibble ----
        float bv_lo = 0.0f; int bi_lo = 0;   // m = 0 scores 0 (all d_n = 0)
        #pragma unroll
        for (int m = 1; m < 16; ++m) {
            float v = 0.0f;
            if (m & 1) v += a[0];
            if (m & 2) v += a[1];
            if (m & 4) v += a[2];
            if (m & 8) v += a[3];
            #pragma unroll
            for (int n = 0; n < N; ++n) {
                int u = eu[n], w = ev[n];
                if (u < 4 && w < 4) {
                    int d = ((m >> u) ^ (m >> w)) & 1;
                    v += d ? bn[n] : 0.0f;
                }
            }
            if (v > bv_lo) { bv_lo = v; bi_lo = m; }
        }
        float bv_hi = 0.0f; int bi_hi = 0;
        #pragma unroll
        for (int m = 1; m < 16; ++m) {
            float v = 0.0f;
            if (m & 1) v += a[4];
            if (m & 2) v += a[5];
            if (m & 4) v += a[6];
            if (m & 8) v += a[7];
            #pragma unroll
            for (int n = 0; n < N; ++n) {
                int u = eu[n], w = ev[n];
                if (u >= 4 && w >= 4) {
                    int d = ((m >> (u - 4)) ^ (m >> (w - 4))) & 1;
                    v += d ? bn[n] : 0.0f;
                }
            }
            if (v > bv_hi) { bv_hi = v; bi_hi = m; }
        }
        best = (bi_hi << 4) | bi_lo;
    } else {
        // ---- generic fallback: enumerate all 256 configs ----
        float bv = -1e30f; best = 0;
        for (int k = 0; k < 256; ++k) {
            float v = 0.0f;
            #pragma unroll
            for (int t = 0; t < T; ++t)
                v += ((k >> t) & 1) ? a[t] : 0.0f;
            #pragma unroll
            for (int n = 0; n < N; ++n) {
                int d = ((k >> eu[n]) ^ (k >> ev[n])) & 1;
                v += d ? bn[n] : 0.0f;
            }
            if (v > bv) { bv = v; best = k; }
        }
    }

    // write MAP states: out[b, t, hw] = bit t of best
    float* os = out + (size_t)b * T * HW + hw;
    #pragma unroll
    for (int t = 0; t < T; ++t)
        os[(size_t)t * HW] = ((best >> t) & 1) ? 1.0f : 0.0f;
}

extern "C" void kernel_launch(void* const* d_in, const int* in_sizes, int n_in,
                              void* d_out, int out_size, void* d_ws, size_t ws_size,
                              hipStream_t stream) {
    const float* o_seg = (const float*)d_in[0];
    const float* o_ch  = (const float*)d_in[1];
    const int*   edges = (const int*)d_in[2];
    float*       out   = (float*)d_out;

    constexpr int TOTAL = 4 * 256 * 256;   // B * H * W pixels
    constexpr int BLOCK = 256;
    map_mrf_kernel<<<TOTAL / BLOCK, BLOCK, 0, stream>>>(o_seg, o_ch, edges, out);
}